// Round 1
// baseline (6177.402 us; speedup 1.0000x reference)
//
#include <hip/hip_runtime.h>
#include <math.h>

// Problem constants
#define B_    32
#define CIN   4
#define SLEN  2048
#define NF    256
#define HD    256          // LSTM hidden per direction
#define SP    341          // post conv+pool sequence length
#define RTOT  (B_*SP)      // 10912 rows
#define NH_   8
#define DH_   64

__device__ __forceinline__ float sigmoidf_(float x) { return 1.0f / (1.0f + expf(-x)); }

// ---------------------------------------------------------------------------
// Kernel 1: Conv1d(4->256,k13,pad6) + BN(eval) + ReLU + MaxPool1d(6) -> x0[b*341+s][co]
// grid (22 s-tiles, 32 b), block 256 (co). Weights live in registers (52/thread).
// ---------------------------------------------------------------------------
__global__ __launch_bounds__(256)
void conv_pool_k(const float* __restrict__ in, const float* __restrict__ cw,
                 const float* __restrict__ gamma, const float* __restrict__ beta,
                 float* __restrict__ x0)
{
    const int b  = blockIdx.y;
    const int s0 = blockIdx.x * 16;
    const int co = threadIdx.x;
    __shared__ float ins[CIN][16*6 + 12];   // [4][108] input window (with halo), zero-padded
    for (int idx = threadIdx.x; idx < CIN*108; idx += 256) {
        int ci = idx / 108, o = idx % 108;
        int pos = 6*s0 - 6 + o;
        ins[ci][o] = (pos >= 0 && pos < SLEN) ? in[(b*CIN + ci)*SLEN + pos] : 0.0f;
    }
    float wreg[52];
    {
        const float4* wp = (const float4*)(cw + co*52);   // 52 floats, 16B aligned
        #pragma unroll
        for (int j4 = 0; j4 < 13; ++j4) {
            float4 w4 = wp[j4];
            wreg[j4*4+0]=w4.x; wreg[j4*4+1]=w4.y; wreg[j4*4+2]=w4.z; wreg[j4*4+3]=w4.w;
        }
    }
    const float scale = gamma[co] * (1.0f / sqrtf(1.0f + 1e-5f));
    const float shift = beta[co];
    __syncthreads();
    for (int si = 0; si < 16; ++si) {
        int s = s0 + si;
        if (s >= SP) break;
        float win[CIN][18];
        #pragma unroll
        for (int ci = 0; ci < CIN; ++ci)
            #pragma unroll
            for (int o = 0; o < 18; ++o)
                win[ci][o] = ins[ci][6*si + o];
        float m = -1e30f;
        #pragma unroll
        for (int p6 = 0; p6 < 6; ++p6) {
            float acc = 0.0f;
            #pragma unroll
            for (int ci = 0; ci < CIN; ++ci)
                #pragma unroll
                for (int kk = 0; kk < 13; ++kk)
                    acc += win[ci][p6+kk] * wreg[ci*13+kk];
            float val = acc * scale + shift;
            val = fmaxf(val, 0.0f);
            m = fmaxf(m, val);
        }
        x0[(size_t)(b*SP + s)*NF + co] = m;
    }
}

// ---------------------------------------------------------------------------
// Kernel 2: generic fp32 GEMM  C[M,N] = act(A[M,K] @ Bw[N,K]^T + bias[N])
// 128x128 tile, 8x8 micro, KC=16, k-major LDS (pad 132) for float4 reads.
// ---------------------------------------------------------------------------
template<int RELU>
__global__ __launch_bounds__(256)
void gemm_k(const float* __restrict__ A, const float* __restrict__ Bw,
            const float* __restrict__ bias, float* __restrict__ C,
            int M, int N, int K)
{
    const int n0 = blockIdx.x * 128;
    const int m0 = blockIdx.y * 128;
    const int tid = threadIdx.x;
    const int tx = tid % 16, ty = tid / 16;
    __shared__ float As[16][132];
    __shared__ float Bs[16][132];
    float acc[8][8];
    #pragma unroll
    for (int i = 0; i < 8; ++i)
        #pragma unroll
        for (int j = 0; j < 8; ++j) acc[i][j] = 0.0f;

    const int lr = tid >> 1;         // 0..127
    const int lc = (tid & 1) * 8;    // 0 or 8

    for (int k0 = 0; k0 < K; k0 += 16) {
        {
            int gm = m0 + lr; if (gm >= M) gm = M - 1;     // clamp (dup rows, stores guarded)
            const float* ap = A + (size_t)gm*K + k0 + lc;
            float4 v0 = *(const float4*)ap;
            float4 v1 = *(const float4*)(ap + 4);
            As[lc+0][lr]=v0.x; As[lc+1][lr]=v0.y; As[lc+2][lr]=v0.z; As[lc+3][lr]=v0.w;
            As[lc+4][lr]=v1.x; As[lc+5][lr]=v1.y; As[lc+6][lr]=v1.z; As[lc+7][lr]=v1.w;
            const float* bp = Bw + (size_t)(n0 + lr)*K + k0 + lc;   // N always %128==0
            float4 u0 = *(const float4*)bp;
            float4 u1 = *(const float4*)(bp + 4);
            Bs[lc+0][lr]=u0.x; Bs[lc+1][lr]=u0.y; Bs[lc+2][lr]=u0.z; Bs[lc+3][lr]=u0.w;
            Bs[lc+4][lr]=u1.x; Bs[lc+5][lr]=u1.y; Bs[lc+6][lr]=u1.z; Bs[lc+7][lr]=u1.w;
        }
        __syncthreads();
        #pragma unroll
        for (int k = 0; k < 16; ++k) {
            float4 a0 = *(const float4*)&As[k][ty*4];
            float4 a1 = *(const float4*)&As[k][ty*4 + 64];
            float4 b0 = *(const float4*)&Bs[k][tx*4];
            float4 b1 = *(const float4*)&Bs[k][tx*4 + 64];
            float av[8] = {a0.x,a0.y,a0.z,a0.w,a1.x,a1.y,a1.z,a1.w};
            float bv[8] = {b0.x,b0.y,b0.z,b0.w,b1.x,b1.y,b1.z,b1.w};
            #pragma unroll
            for (int i = 0; i < 8; ++i)
                #pragma unroll
                for (int j = 0; j < 8; ++j)
                    acc[i][j] += av[i] * bv[j];
        }
        __syncthreads();
    }
    #pragma unroll
    for (int ih = 0; ih < 2; ++ih) {
        #pragma unroll
        for (int ii = 0; ii < 4; ++ii) {
            int m = m0 + ih*64 + ty*4 + ii;
            if (m >= M) continue;
            #pragma unroll
            for (int jh = 0; jh < 2; ++jh) {
                int n = n0 + jh*64 + tx*4;
                float4 bb = *(const float4*)&bias[n];
                float4 r;
                r.x = acc[ih*4+ii][jh*4+0] + bb.x;
                r.y = acc[ih*4+ii][jh*4+1] + bb.y;
                r.z = acc[ih*4+ii][jh*4+2] + bb.z;
                r.w = acc[ih*4+ii][jh*4+3] + bb.w;
                if (RELU) {
                    r.x = fmaxf(r.x, 0.f); r.y = fmaxf(r.y, 0.f);
                    r.z = fmaxf(r.z, 0.f); r.w = fmaxf(r.w, 0.f);
                }
                *(float4*)&C[(size_t)m*N + n] = r;
            }
        }
    }
}

// ---------------------------------------------------------------------------
// Kernel 3: one LSTM step (both directions): gates = G[t] + h_in @ Whh^T, cell update.
// G[r][d*1024 + g*256 + j] already holds x-part + bias. h double-buffered across steps.
// grid (8 j-tiles, 11 n-tiles, 2 dirs), block 256, tile [32n x 32j] (128 gate cols), K=256.
// ---------------------------------------------------------------------------
__global__ __launch_bounds__(256)
void lstm_step_k(const float* __restrict__ G,     // [RTOT][2048]
                 const float* __restrict__ Whh,   // [2][1024][256]
                 const float* __restrict__ h_in,  // [2][341][256]
                 float* __restrict__ h_out,
                 float* __restrict__ c_st,
                 float* __restrict__ x_out,       // [RTOT][512]
                 int s)
{
    const int d = blockIdx.z;
    const int t_in = d ? (B_ - 1 - s) : s;
    const int n0 = blockIdx.y * 32;
    const int j0 = blockIdx.x * 32;
    const int tid = threadIdx.x;
    const int tx = tid % 16, ty = tid / 16;
    __shared__ float hs[32][68];
    __shared__ float ws[128][68];
    float acc[2][2][4];
    #pragma unroll
    for (int a = 0; a < 2; ++a)
        #pragma unroll
        for (int c = 0; c < 2; ++c)
            #pragma unroll
            for (int g = 0; g < 4; ++g) acc[a][c][g] = 0.0f;

    for (int k0 = 0; k0 < 256; k0 += 64) {
        {   // stage h tile [32][64]
            int r = tid >> 3, c8 = (tid & 7) * 8;
            int n = n0 + r; if (n > SP-1) n = SP-1;
            const float* hp = h_in + ((size_t)d*SP + n)*HD + k0 + c8;
            float4 v0 = *(const float4*)hp;
            float4 v1 = *(const float4*)(hp + 4);
            *(float4*)&hs[r][c8]   = v0;
            *(float4*)&hs[r][c8+4] = v1;
        }
        {   // stage Whh tile [128 gate-cols][64]
            int jr = tid >> 1, half = tid & 1;
            int g = jr >> 5, jl = jr & 31;
            int jc = g*256 + j0 + jl;
            const float* wp = Whh + ((size_t)d*1024 + jc)*HD + k0 + half*32;
            #pragma unroll
            for (int u4 = 0; u4 < 8; ++u4)
                *(float4*)&ws[jr][half*32 + u4*4] = *(const float4*)(wp + u4*4);
        }
        __syncthreads();
        #pragma unroll
        for (int k = 0; k < 64; k += 4) {
            float4 a0 = *(const float4*)&hs[ty][k];
            float4 a1 = *(const float4*)&hs[ty+16][k];
            #pragma unroll
            for (int g = 0; g < 4; ++g) {
                float4 b0 = *(const float4*)&ws[g*32 + tx][k];
                float4 b1 = *(const float4*)&ws[g*32 + tx + 16][k];
                acc[0][0][g] += a0.x*b0.x + a0.y*b0.y + a0.z*b0.z + a0.w*b0.w;
                acc[0][1][g] += a0.x*b1.x + a0.y*b1.y + a0.z*b1.z + a0.w*b1.w;
                acc[1][0][g] += a1.x*b0.x + a1.y*b0.y + a1.z*b0.z + a1.w*b0.w;
                acc[1][1][g] += a1.x*b1.x + a1.y*b1.y + a1.z*b1.z + a1.w*b1.w;
            }
        }
        __syncthreads();
    }
    #pragma unroll
    for (int ni = 0; ni < 2; ++ni) {
        int n = n0 + ty + ni*16;
        if (n >= SP) continue;
        #pragma unroll
        for (int ji = 0; ji < 2; ++ji) {
            int j = j0 + tx + ji*16;
            size_t gb = ((size_t)t_in*SP + n)*2048 + (size_t)d*1024;
            float gi = acc[ni][ji][0] + G[gb + j];
            float gf = acc[ni][ji][1] + G[gb + 256 + j];
            float gg = acc[ni][ji][2] + G[gb + 512 + j];
            float go = acc[ni][ji][3] + G[gb + 768 + j];
            size_t ci_ = ((size_t)d*SP + n)*HD + j;
            float c_old = c_st[ci_];
            float cn = sigmoidf_(gf)*c_old + sigmoidf_(gi)*tanhf(gg);
            float hn = sigmoidf_(go)*tanhf(cn);
            c_st[ci_] = cn;
            h_out[ci_] = hn;
            x_out[((size_t)t_in*SP + n)*512 + d*HD + j] = hn;
        }
    }
}

// ---------------------------------------------------------------------------
// Kernel 4: attention for one (head, batch, 16-q-row tile).
// scores = (q.k/8) / rpe  -> softmax -> relu(P@V / sum) -> cat[r][h*64+d]
// RPE computed analytically: maxpool9x9/s6/p1 of |k-q|/2047 == max(|c1-r0|,|r1-c0|)/2047.
// ---------------------------------------------------------------------------
__global__ __launch_bounds__(256)
void attn_k(const float* __restrict__ q, const float* __restrict__ k,
            const float* __restrict__ v, float* __restrict__ cat)
{
    const int h = blockIdx.z, b = blockIdx.y;
    const int q0 = blockIdx.x * 16;
    const int tid = threadIdx.x;
    __shared__ float qs[16][68];
    __shared__ float ks[128][68];
    __shared__ float sc[16][348];
    __shared__ float rsum[16];
    {   // stage q tile [16][64]
        int r = tid >> 4, c4 = (tid & 15) * 4;
        int qq = q0 + r; if (qq > SP-1) qq = SP-1;
        *(float4*)&qs[r][c4] = *(const float4*)&q[((size_t)b*SP + qq)*512 + h*64 + c4];
    }
    const int stx = tid % 32, sty = tid / 32;   // k-quad, q-pair
    for (int p = 0; p < 3; ++p) {
        int kk0 = p * 128;
        {   // stage k tile [128][64]
            int jr = tid >> 1, half = tid & 1;
            int kr = kk0 + jr; if (kr > SP-1) kr = SP-1;
            const float* kp = &k[((size_t)b*SP + kr)*512 + h*64 + half*32];
            #pragma unroll
            for (int u4 = 0; u4 < 8; ++u4)
                *(float4*)&ks[jr][half*32 + u4*4] = *(const float4*)(kp + u4*4);
        }
        __syncthreads();
        float acc[2][4] = {{0.f,0.f,0.f,0.f},{0.f,0.f,0.f,0.f}};
        #pragma unroll
        for (int kd = 0; kd < 64; kd += 4) {
            float4 a0 = *(const float4*)&qs[sty*2][kd];
            float4 a1 = *(const float4*)&qs[sty*2+1][kd];
            #pragma unroll
            for (int j = 0; j < 4; ++j) {
                float4 bb = *(const float4*)&ks[stx*4 + j][kd];
                acc[0][j] += a0.x*bb.x + a0.y*bb.y + a0.z*bb.z + a0.w*bb.w;
                acc[1][j] += a1.x*bb.x + a1.y*bb.y + a1.z*bb.z + a1.w*bb.w;
            }
        }
        #pragma unroll
        for (int i = 0; i < 2; ++i) {
            int qq = q0 + sty*2 + i;
            int r0 = 6*qq - 1; if (r0 < 0) r0 = 0;
            int r1 = 6*qq + 7; if (r1 > SLEN-1) r1 = SLEN-1;
            #pragma unroll
            for (int j = 0; j < 4; ++j) {
                int kk = kk0 + stx*4 + j;
                if (kk < SP) {
                    int c0 = 6*kk - 1; if (c0 < 0) c0 = 0;
                    int c1 = 6*kk + 7;                      // kk<=340 -> <=2047
                    int dd1 = c1 - r0; if (dd1 < 0) dd1 = -dd1;
                    int dd2 = r1 - c0; if (dd2 < 0) dd2 = -dd2;
                    int den = dd1 > dd2 ? dd1 : dd2;
                    sc[sty*2+i][kk] = (acc[i][j] * 0.125f) * 2047.0f / (float)den;
                }
            }
        }
        __syncthreads();
    }
    {   // softmax per row (16 lanes/row); keep exp() in sc, 1/sum applied in epilogue
        int row = tid >> 4, sub = tid & 15;
        float m = -1e30f;
        for (int kk = sub; kk < SP; kk += 16) m = fmaxf(m, sc[row][kk]);
        #pragma unroll
        for (int o = 1; o < 16; o <<= 1) m = fmaxf(m, __shfl_xor(m, o, 64));
        float ssum = 0.0f;
        for (int kk = sub; kk < SP; kk += 16) {
            float e = expf(sc[row][kk] - m);
            sc[row][kk] = e;
            ssum += e;
        }
        #pragma unroll
        for (int o = 1; o < 16; o <<= 1) ssum += __shfl_xor(ssum, o, 64);
        if (sub == 0) rsum[row] = ssum;
        if (tid < 112) { int rr = tid / 7, cc = SP + tid % 7; sc[rr][cc] = 0.0f; }  // zero pad cols 341..347
    }
    __syncthreads();
    // PV: acc[2q][2d] over K=341 (padded to 344), V staged in chunks of 64 rows
    float (*vs)[68] = (float(*)[68])ks;
    const int dtx = tid % 32, dty = tid / 32;
    float acc2[2][2] = {{0.f,0.f},{0.f,0.f}};
    for (int kk0 = 0; kk0 < SP; kk0 += 64) {
        int len = 344 - kk0; if (len > 64) len = 64;
        {
            int jr = tid >> 2, c16 = (tid & 3) * 16;
            int kr = kk0 + jr;
            if (kr <= SP-1) {
                const float* vp = &v[((size_t)b*SP + kr)*512 + h*64 + c16];
                #pragma unroll
                for (int u4 = 0; u4 < 4; ++u4)
                    *(float4*)&vs[jr][c16 + u4*4] = *(const float4*)(vp + u4*4);
            } else {
                float4 z = {0.f,0.f,0.f,0.f};
                #pragma unroll
                for (int u4 = 0; u4 < 4; ++u4)
                    *(float4*)&vs[jr][c16 + u4*4] = z;
            }
        }
        __syncthreads();
        for (int kk = 0; kk < len; kk += 4) {
            float4 a0 = *(const float4*)&sc[dty*2][kk0 + kk];
            float4 a1 = *(const float4*)&sc[dty*2+1][kk0 + kk];
            float a0v[4] = {a0.x, a0.y, a0.z, a0.w};
            float a1v[4] = {a1.x, a1.y, a1.z, a1.w};
            #pragma unroll
            for (int jq = 0; jq < 4; ++jq) {
                float2 vv = *(const float2*)&vs[kk + jq][dtx*2];
                acc2[0][0] += a0v[jq]*vv.x; acc2[0][1] += a0v[jq]*vv.y;
                acc2[1][0] += a1v[jq]*vv.x; acc2[1][1] += a1v[jq]*vv.y;
            }
        }
        __syncthreads();
    }
    #pragma unroll
    for (int i = 0; i < 2; ++i) {
        int qq = q0 + dty*2 + i;
        if (qq < SP) {
            float inv = 1.0f / rsum[dty*2 + i];
            float2 r;
            r.x = fmaxf(acc2[i][0]*inv, 0.0f);
            r.y = fmaxf(acc2[i][1]*inv, 0.0f);
            *(float2*)&cat[((size_t)b*SP + qq)*512 + h*64 + dtx*2] = r;
        }
    }
}

// ---------------------------------------------------------------------------
extern "C" void kernel_launch(void* const* d_in, const int* in_sizes, int n_in,
                              void* d_out, int out_size, void* d_ws, size_t ws_size,
                              hipStream_t stream)
{
    (void)in_sizes; (void)n_in; (void)out_size; (void)ws_size;
    const float* in    = (const float*)d_in[0];
    const float* cw    = (const float*)d_in[1];
    const float* gamma = (const float*)d_in[2];
    const float* beta  = (const float*)d_in[3];
    const float* Wih0  = (const float*)d_in[4];
    const float* Whh0  = (const float*)d_in[5];
    const float* b0    = (const float*)d_in[6];
    const float* Wih1  = (const float*)d_in[7];
    const float* Whh1  = (const float*)d_in[8];
    const float* b1    = (const float*)d_in[9];
    const float* Qw    = (const float*)d_in[10];
    const float* Qb    = (const float*)d_in[11];
    const float* Kw    = (const float*)d_in[12];
    const float* Kb    = (const float*)d_in[13];
    const float* Vw    = (const float*)d_in[14];
    const float* Vb    = (const float*)d_in[15];
    const float* mhw   = (const float*)d_in[16];
    const float* mhb   = (const float*)d_in[17];
    float* out = (float*)d_out;

    // workspace arena (floats). Total ~147 MB.
    float* x0 = (float*)d_ws;                                   //  2,793,472
    float* G  = x0 + (size_t)RTOT*NF;                           // 22,347,776 (reused for q,k,v)
    float* x1 = G  + (size_t)RTOT*2048;                         //  5,586,944 (reused for cat)
    float* x2 = x1 + (size_t)RTOT*512;                          //  5,586,944
    float* hb = x2 + (size_t)RTOT*512;                          //  2 * 174,592 (h double buffer)
    float* cb = hb + (size_t)2*2*SP*HD;                         //  174,592
    float* qbuf = G;
    float* kbuf = G + (size_t)RTOT*512;
    float* vbuf = G + (size_t)2*RTOT*512;
    float* cat  = x1;
    const size_t hsz = (size_t)2*SP*HD;

    // 1. conv+bn+relu+pool
    conv_pool_k<<<dim3(22, B_), 256, 0, stream>>>(in, cw, gamma, beta, x0);
    // 2. layer-1 input gates: G = x0 @ Wih0^T + b0   [10912 x 2048], K=256
    gemm_k<0><<<dim3(16, 86), 256, 0, stream>>>(x0, Wih0, b0, G, RTOT, 2048, 256);
    // 3. layer-1 scan (32 steps, both dirs)
    hipMemsetAsync(hb, 0, 2*hsz*sizeof(float), stream);
    hipMemsetAsync(cb, 0, hsz*sizeof(float), stream);
    for (int s = 0; s < B_; ++s) {
        float* hin  = hb + (size_t)(s & 1) * hsz;
        float* hout = hb + (size_t)((s+1) & 1) * hsz;
        lstm_step_k<<<dim3(8, 11, 2), 256, 0, stream>>>(G, Whh0, hin, hout, cb, x1, s);
    }
    // 4. layer-2 input gates: G = x1 @ Wih1^T + b1, K=512
    gemm_k<0><<<dim3(16, 86), 256, 0, stream>>>(x1, Wih1, b1, G, RTOT, 2048, 512);
    // 5. layer-2 scan
    hipMemsetAsync(hb, 0, 2*hsz*sizeof(float), stream);
    hipMemsetAsync(cb, 0, hsz*sizeof(float), stream);
    for (int s = 0; s < B_; ++s) {
        float* hin  = hb + (size_t)(s & 1) * hsz;
        float* hout = hb + (size_t)((s+1) & 1) * hsz;
        lstm_step_k<<<dim3(8, 11, 2), 256, 0, stream>>>(G, Whh1, hin, hout, cb, x2, s);
    }
    // 6. Q/K/V projections (flattened per-head weights are plain [512][512] GEMMs)
    gemm_k<0><<<dim3(4, 86), 256, 0, stream>>>(x2, Qw, Qb, qbuf, RTOT, 512, 512);
    gemm_k<0><<<dim3(4, 86), 256, 0, stream>>>(x2, Kw, Kb, kbuf, RTOT, 512, 512);
    gemm_k<0><<<dim3(4, 86), 256, 0, stream>>>(x2, Vw, Vb, vbuf, RTOT, 512, 512);
    // 7. relative-position attention + relu -> cat
    attn_k<<<dim3(22, B_, NH_), 256, 0, stream>>>(qbuf, kbuf, vbuf, cat);
    // 8. final linear + relu -> out
    gemm_k<1><<<dim3(4, 86), 256, 0, stream>>>(cat, mhw, mhb, out, RTOT, 512, 512);
}